// Round 15
// baseline (1035.844 us; speedup 1.0000x reference)
//
#include <hip/hip_runtime.h>
#include <hip/hip_bf16.h>

typedef unsigned int u32;
typedef unsigned long long u64;
typedef unsigned short u16;

typedef float f32x4 __attribute__((ext_vector_type(4)));
typedef __bf16 bf16x8 __attribute__((ext_vector_type(8)));
typedef unsigned short u16x8 __attribute__((ext_vector_type(8)));
typedef unsigned short u16x4 __attribute__((ext_vector_type(4)));

#define NA 36864          // 64*64*9 anchors
#define PRE_NMS 6000
#define NPROP 1000
#define KROI 50176        // 14*14*256
#define MASKW 94          // ceil(6000/64)
#define MASKT_STRIDE 6144 // padded row stride of transposed mask
#define KSPLIT 8
#define KCHUNK (KROI / KSPLIT)  // 6272
#define BN_EPS 1e-3f
#define CONV_TILES 3136   // 196 k-groups (4x64 rows each) x 16 n-tiles of w_rc1

__device__ __forceinline__ u16 f2bf(float v) {
    __bf16 h = (__bf16)v;
    return __builtin_bit_cast(u16, h);
}
__device__ __forceinline__ bf16x8 ldfrag(const u16* p) {
    return __builtin_bit_cast(bf16x8, *(const u16x8*)p);
}
__device__ __forceinline__ void gload16(const void* g, void* l) {
    __builtin_amdgcn_global_load_lds(
        (const __attribute__((address_space(1))) unsigned int*)g,
        (__attribute__((address_space(3))) unsigned int*)l, 16, 0, 0);
}

// ---------------------------------------------------------------------------
// gemm_v3: fp32 partial GEMM. part[ks] = A[M][kchunk-slice] @ B[.][N].
// 128x64 tile, 128 threads, 8x8 per thread, double-buffered LDS.
// Structural ceiling ~50% VALUBusy (LDS-instruction-bound): gemm_v4 spilled,
// deeper K-split (R12) was occupancy-neutral. Do not re-attempt.
// CONV3: A is implicit im2col of X[64][64][256], 3x3 SAME (K = 2304).
// ---------------------------------------------------------------------------
template <bool CONV3>
__global__ __launch_bounds__(128) void gemm_v3(
    const float* __restrict__ A, const float* __restrict__ B, float* __restrict__ part,
    int M, int N, int K, int kchunk) {
    __shared__ float As[2][16][132];
    __shared__ float Bs[2][16][68];
    const int tid = threadIdx.x;
    const int bm = blockIdx.x * 128, bn = blockIdx.y * 64;
    const int ks = blockIdx.z;
    const int kbeg = ks * kchunk, kend = kbeg + kchunk;
    const int tx = tid & 7, ty = tid >> 3;
    (void)K;

    float4 ra[4], rb[2];
    auto loadA = [&](int k0, int i) -> float4 {
        int e = tid + 128 * i;  // 0..511
        int m = e >> 2, kq = (e & 3) * 4;
        float4 v = {0.f, 0.f, 0.f, 0.f};
        int gm = bm + m;
        if (CONV3) {
            int gg = k0 >> 8;
            int dy = gg / 3, dx = gg - 3 * dy;
            int pr = gm >> 6, pc = gm & 63;
            int sr = pr + dy - 1, sc = pc + dx - 1;
            int ch = (k0 & 255) + kq;
            if (sr >= 0 && sr < 64 && sc >= 0 && sc < 64)
                v = *(const float4*)&A[(size_t)((sr << 6) + sc) * 256 + ch];
        } else {
            if (gm < M) v = *(const float4*)&A[(size_t)gm * K + k0 + kq];
        }
        return v;
    };
    auto loadB = [&](int k0, int i) -> float4 {
        int e = tid + 128 * i;  // 0..255
        int n4 = (e & 15) * 4, kk = e >> 4;
        return *(const float4*)&B[(size_t)(k0 + kk) * N + bn + n4];
    };
    auto stage = [&](int s) {
#pragma unroll
        for (int i = 0; i < 4; ++i) {
            int e = tid + 128 * i; int m = e >> 2, kq = (e & 3) * 4;
            As[s][kq + 0][m] = ra[i].x; As[s][kq + 1][m] = ra[i].y;
            As[s][kq + 2][m] = ra[i].z; As[s][kq + 3][m] = ra[i].w;
        }
#pragma unroll
        for (int i = 0; i < 2; ++i) {
            int e = tid + 128 * i; int n4 = (e & 15) * 4, kk = e >> 4;
            *(float4*)&Bs[s][kk][n4] = rb[i];
        }
    };

    float acc[8][8] = {};
#pragma unroll
    for (int i = 0; i < 4; ++i) ra[i] = loadA(kbeg, i);
#pragma unroll
    for (int i = 0; i < 2; ++i) rb[i] = loadB(kbeg, i);
    stage(0);
    if (kbeg + 16 < kend) {
#pragma unroll
        for (int i = 0; i < 4; ++i) ra[i] = loadA(kbeg + 16, i);
#pragma unroll
        for (int i = 0; i < 2; ++i) rb[i] = loadB(kbeg + 16, i);
    }
    __syncthreads();
    int s = 0;
    for (int k0 = kbeg; k0 < kend; k0 += 16) {
        if (k0 + 16 < kend) {
            stage(s ^ 1);
            if (k0 + 32 < kend) {
#pragma unroll
                for (int i = 0; i < 4; ++i) ra[i] = loadA(k0 + 32, i);
#pragma unroll
                for (int i = 0; i < 2; ++i) rb[i] = loadB(k0 + 32, i);
            }
        }
#pragma unroll
        for (int kk = 0; kk < 16; ++kk) {
            float4 a0 = *(const float4*)&As[s][kk][8 * ty];
            float4 a1 = *(const float4*)&As[s][kk][8 * ty + 4];
            float4 b0 = *(const float4*)&Bs[s][kk][8 * tx];
            float4 b1 = *(const float4*)&Bs[s][kk][8 * tx + 4];
            const float av[8] = {a0.x, a0.y, a0.z, a0.w, a1.x, a1.y, a1.z, a1.w};
            const float bv[8] = {b0.x, b0.y, b0.z, b0.w, b1.x, b1.y, b1.z, b1.w};
#pragma unroll
            for (int r = 0; r < 8; ++r)
#pragma unroll
                for (int c = 0; c < 8; ++c) acc[r][c] = fmaf(av[r], bv[c], acc[r][c]);
        }
        __syncthreads();
        s ^= 1;
    }
    float* P = part + (size_t)ks * ((size_t)M * N);
#pragma unroll
    for (int r = 0; r < 8; ++r) {
        int gm = bm + 8 * ty + r;
        if (gm >= M) continue;
        *(float4*)&P[(size_t)gm * N + bn + 8 * tx] = *(const float4*)&acc[r][0];
        *(float4*)&P[(size_t)gm * N + bn + 8 * tx + 4] = *(const float4*)&acc[r][4];
    }
}

// ---------------------------------------------------------------------------
// reduce K-split partials + bias + epilogue. EPI: 0 none, 1 relu, 2 bn+relu.
// ---------------------------------------------------------------------------
template <int EPI>
__global__ __launch_bounds__(256) void reduce_part(
    const float* __restrict__ part, float* __restrict__ C, int M, int N, int KS,
    const float* __restrict__ bias, const float* __restrict__ g,
    const float* __restrict__ be, const float* __restrict__ mu,
    const float* __restrict__ var) {
    int i = blockIdx.x * 256 + threadIdx.x;
    int total = (M * N) >> 2;
    if (i >= total) return;
    size_t off = (size_t)i * 4;
    int n = (int)(off % (size_t)N);
    size_t slice = (size_t)M * N;
    float4 sv = {0.f, 0.f, 0.f, 0.f};
    for (int k = 0; k < KS; ++k) {
        float4 v = *(const float4*)&part[(size_t)k * slice + off];
        sv.x += v.x; sv.y += v.y; sv.z += v.z; sv.w += v.w;
    }
    float o[4] = {sv.x, sv.y, sv.z, sv.w};
#pragma unroll
    for (int j = 0; j < 4; ++j) {
        float v = o[j] + bias[n + j];
        if constexpr (EPI == 1) v = fmaxf(v, 0.f);
        if constexpr (EPI == 2) {
            float sc = g[n + j] / sqrtf(var[n + j] + BN_EPS);
            v = (v - mu[n + j]) * sc + be[n + j];
            v = fmaxf(v, 0.f);
        }
        o[j] = v;
    }
    *(float4*)&C[off] = *(const float4*)&o[0];
}

// pack w_cls [512][18] + w_dlt [512][36] -> wCat [512][64] (zero pad), bCat[64]
__global__ __launch_bounds__(256) void pack_heads(
    const float* __restrict__ wc, const float* __restrict__ wd,
    const float* __restrict__ bc, const float* __restrict__ bd,
    float* __restrict__ wCat, float* __restrict__ bCat) {
    int i = blockIdx.x * 256 + threadIdx.x;
    if (i < 512 * 64) {
        int k = i >> 6, n = i & 63;
        float v = 0.f;
        if (n < 18) v = wc[k * 18 + n];
        else if (n < 54) v = wd[k * 36 + (n - 18)];
        wCat[i] = v;
    }
    if (i < 64) bCat[i] = (i < 18) ? bc[i] : ((i < 54) ? bd[i - 18] : 0.f);
}

// pack w_log [1024][81] + w_bfc [1024][324] -> wHead [1024][512] (pad), bHead[512]
__global__ __launch_bounds__(256) void pack_roi_heads(
    const float* __restrict__ wl, const float* __restrict__ wb,
    const float* __restrict__ bl, const float* __restrict__ bb,
    float* __restrict__ wH, float* __restrict__ bH) {
    int i = blockIdx.x * 256 + threadIdx.x;
    if (i < 1024 * 512) {
        int k = i >> 9, n = i & 511;
        float v = 0.f;
        if (n < 81) v = wl[k * 81 + n];
        else if (n < 405) v = wb[k * 324 + (n - 81)];
        wH[i] = v;
    }
    if (i < 512) bH[i] = (i < 81) ? bl[i] : ((i < 405) ? bb[i - 81] : 0.f);
}

// hroi [1000][512] cols 81..404 -> out4 [1000][324]
__global__ __launch_bounds__(256) void split_roi(
    const float* __restrict__ hr, float* __restrict__ out4) {
    int i = blockIdx.x * 256 + threadIdx.x;
    if (i >= NPROP * 324) return;
    int r = i / 324, c = i - r * 324;
    out4[i] = hr[r * 512 + 81 + c];
}

// ---------------------------------------------------------------------------
// RPN softmax pair + delta copy (from hcat [4096][64]) -> out0, out1, keys
// ---------------------------------------------------------------------------
__global__ __launch_bounds__(256) void rpn_probs_keys(
    const float* __restrict__ hc, float* __restrict__ out0, float* __restrict__ out1,
    u64* __restrict__ keys) {
    int i = blockIdx.x * 256 + threadIdx.x;
    if (i >= NA) return;
    int cell = i / 9, a = i - cell * 9;
    const float* row = &hc[cell * 64];
    float l0 = row[2 * a], l1 = row[2 * a + 1];
    float m = fmaxf(l0, l1);
    float e0 = expf(l0 - m), e1 = expf(l1 - m);
    float ssum = e0 + e1;
    float p0 = e0 / ssum, p1 = e1 / ssum;
    out0[2 * i] = p0;
    out0[2 * i + 1] = p1;
    keys[i] = ((u64)__float_as_uint(p1) << 32) | (u64)(0xFFFFFFFFu - (u32)i);
    const float* src = row + 18 + 4 * a;
    float4 d = {src[0], src[1], src[2], src[3]};
    *(float4*)&out1[(size_t)i * 4] = d;
}

// ---------------------------------------------------------------------------
// Exact 6000-th largest key via 8-pass MSB radix select, then compact the
// 6000 qualifying keys into skeys (fused; single block, 1024 threads).
// ---------------------------------------------------------------------------
__global__ __launch_bounds__(1024) void radix_select_compact(
    const u64* __restrict__ keys, u64* __restrict__ skeys) {
    __shared__ u32 hist[256];
    __shared__ u64 sPrefix, sMask;
    __shared__ int sRank;
    __shared__ u32 sCount;
    int tid = threadIdx.x;
    if (tid == 0) { sPrefix = 0; sMask = 0; sRank = PRE_NMS; sCount = 0; }
    __syncthreads();
    for (int p = 56; p >= 0; p -= 8) {
        if (tid < 256) hist[tid] = 0;
        __syncthreads();
        u64 pref = sPrefix, msk = sMask;
        for (int i = tid; i < NA; i += 1024) {
            u64 k = keys[i];
            if ((k & msk) == pref) atomicAdd(&hist[(u32)((k >> p) & 255)], 1u);
        }
        __syncthreads();
        if (tid == 0) {
            int cum = 0, rank = sRank, sel = 0;
            for (int d = 255; d >= 0; --d) {
                int c = (int)hist[d];
                if (cum + c >= rank) { sel = d; sRank = rank - cum; break; }
                cum += c;
            }
            sPrefix = pref | ((u64)(u32)sel << p);
            sMask = msk | (0xFFull << p);
        }
        __syncthreads();
    }
    u64 thr = sPrefix;
    for (int i = tid; i < NA; i += 1024) {
        u64 k = keys[i];
        if (k >= thr) {
            u32 pos = atomicAdd(&sCount, 1u);
            skeys[pos] = k;
        }
    }
}

// ---------------------------------------------------------------------------
// Fused rank-sort + decode: exact descending rank by LDS counting (keys
// unique), decode box, write props[rank] directly.
// ---------------------------------------------------------------------------
__global__ __launch_bounds__(256) void rank_decode(
    const u64* __restrict__ skeys, const float* __restrict__ deltas,
    const int* __restrict__ ih, const int* __restrict__ iw, float* __restrict__ props) {
    __shared__ u64 lds[PRE_NMS];
    const int tid = threadIdx.x;
    for (int i = tid; i < PRE_NMS; i += 256) lds[i] = skeys[i];
    __syncthreads();
    int i = blockIdx.x * 256 + tid;
    if (i >= PRE_NMS) return;
    u64 k = lds[i];
    int c = 0;
#pragma unroll 4
    for (int j = 0; j < PRE_NMS; ++j) c += (lds[j] > k) ? 1 : 0;
    u32 idx = 0xFFFFFFFFu - (u32)(k & 0xFFFFFFFFull);
    float H = (float)(*ih), W = (float)(*iw);
    int a = idx % 9;
    int cell = idx / 9;
    int r = cell >> 6, cc = cell & 63;
    float sy = H / 64.0f, sx = W / 64.0f;
    float cy = ((float)r + 0.5f) * sy, cx = ((float)cc + 0.5f) * sx;
    const float scales[3] = {64.f, 128.f, 256.f};
    const float ratios[3] = {0.5f, 1.f, 2.f};
    float sq = sqrtf(ratios[a % 3]);
    float scl = scales[a / 3];
    float ah = scl * sq, aw = scl / sq;
    float ay1 = cy - ah * 0.5f, ax1 = cx - aw * 0.5f;
    float h = ah, w = aw;
    float d0 = deltas[(size_t)idx * 4 + 0], d1 = deltas[(size_t)idx * 4 + 1];
    float d2 = deltas[(size_t)idx * 4 + 2], d3 = deltas[(size_t)idx * 4 + 3];
    float ncy = ay1 + 0.5f * h + d0 * h;
    float ncx = ax1 + 0.5f * w + d1 * w;
    float nh = h * expf(d2), nw = w * expf(d3);
    float y1 = ncy - 0.5f * nh, x1 = ncx - 0.5f * nw;
    float y2 = ncy + 0.5f * nh, x2 = ncx + 0.5f * nw;
    float4 box = {fminf(fmaxf(y1, 0.f), H) / H, fminf(fmaxf(x1, 0.f), W) / W,
                  fminf(fmaxf(y2, 0.f), H) / H, fminf(fmaxf(x2, 0.f), W) / W};
    *(float4*)&props[(size_t)c * 4] = box;
}

// ---------------------------------------------------------------------------
// NMS: transposed pairwise suppression bitmask + diag words.
// Chunk (j) boxes staged once per block in LDS; inner loop is LDS broadcast.
// ---------------------------------------------------------------------------
__global__ __launch_bounds__(256) void nms_masks(
    const float* __restrict__ props, u64* __restrict__ masksT, u64* __restrict__ diag) {
    __shared__ float4 chunk[64];
    int tid = threadIdx.x;
    int i = blockIdx.x * 256 + tid;
    int w = blockIdx.y;
    int jbase = w * 64;
    if (tid < 64 && jbase + tid < PRE_NMS)
        chunk[tid] = *(const float4*)&props[(size_t)(jbase + tid) * 4];
    __syncthreads();
    if (i >= PRE_NMS) return;
    float4 bi = *(const float4*)&props[(size_t)i * 4];
    float y1 = bi.x, x1 = bi.y, y2 = bi.z, x2 = bi.w;
    float ai = (y2 - y1) * (x2 - x1);
    u64 bits = 0;
    int lim = PRE_NMS - jbase; if (lim > 64) lim = 64;
    for (int b = 0; b < lim; ++b) {
        float4 bj = chunk[b];
        float iy1 = fmaxf(y1, bj.x), ix1 = fmaxf(x1, bj.y);
        float iy2 = fminf(y2, bj.z), ix2 = fminf(x2, bj.w);
        float inter = fmaxf(iy2 - iy1, 0.f) * fmaxf(ix2 - ix1, 0.f);
        float aj = (bj.z - bj.x) * (bj.w - bj.y);
        float iou = inter / (ai + aj - inter + 1e-8f);
        if (iou > 0.7f) bits |= (1ull << b);
    }
    masksT[(size_t)w * MASKT_STRIDE + i] = bits;
    if (w == (i >> 6)) diag[i] = bits;
}

// ---------------------------------------------------------------------------
// Fused: block 0 = lazy chunked greedy NMS + proposal writeout (per-wave OR
// slots, no LDS atomics); blocks 1.. = w_rc1 -> bf16^T, 4 k-tiles per block
// (4 loads in flight before first barrier -> latency amortized).
// ---------------------------------------------------------------------------
__global__ __launch_bounds__(1024) void nms_greedy_conv(
    const u64* __restrict__ masksT, const u64* __restrict__ diag,
    const float* __restrict__ props, float* __restrict__ out2,
    const float* __restrict__ Wf, u16* __restrict__ WT) {
    __shared__ u64 sdiag[PRE_NMS];
    __shared__ int skept[NPROP];
    __shared__ u64 swpart[16];
    __shared__ int skcount;
    const int tid = threadIdx.x;

    if (blockIdx.x != 0) {
        // ---- conversion role: 4 consecutive 64-row k-tiles x one n-tile ----
        u16* tile = (u16*)sdiag;  // [4][64][68] u16 = 34816 B alias
        int bid = blockIdx.x - 1;
        int kg = bid % 196, n0 = (bid / 196) * 64;
        int k0 = kg * 256;
        int kk = tid >> 4, n4 = (tid & 15) * 4;
        float4 v[4];
#pragma unroll
        for (int t = 0; t < 4; ++t)
            v[t] = *(const float4*)&Wf[(size_t)(k0 + t * 64 + kk) * 1024 + n0 + n4];
#pragma unroll
        for (int t = 0; t < 4; ++t) {
            u16* tt = tile + t * 64 * 68;
            tt[(n4 + 0) * 68 + kk] = f2bf(v[t].x);
            tt[(n4 + 1) * 68 + kk] = f2bf(v[t].y);
            tt[(n4 + 2) * 68 + kk] = f2bf(v[t].z);
            tt[(n4 + 3) * 68 + kk] = f2bf(v[t].w);
        }
        __syncthreads();
        int nn = tid >> 4, k4 = (tid & 15) * 4;
#pragma unroll
        for (int t = 0; t < 4; ++t) {
            u16x4 o = *(const u16x4*)&tile[(t * 64 + nn) * 68 + k4];
            *(u16x4*)&WT[(size_t)(n0 + nn) * KROI + k0 + t * 64 + k4] = o;
        }
        return;
    }

    // ---- greedy role (block 0) ----
    const int lane = tid & 63;
    const int wid = tid >> 6;
    for (int i = tid; i < PRE_NMS; i += 1024) sdiag[i] = diag[i];
    if (tid == 0) skcount = 0;
    __syncthreads();
    int kept = 0;  // meaningful in wave 0 only
    for (int c = 0; c < MASKW; ++c) {
        int keptNow = skcount;
        if (keptNow >= NPROP) break;
        u64 acc = 0;
        const u64* mrow = masksT + (size_t)c * MASKT_STRIDE;
        for (int t = tid; t < keptNow; t += 1024) acc |= mrow[skept[t]];
#pragma unroll
        for (int s = 32; s > 0; s >>= 1) acc |= __shfl_xor(acc, s);
        if (lane == 0) swpart[wid] = acc;
        __syncthreads();
        if (tid < 64) {
            u64 removed = 0;
#pragma unroll
            for (int q = 0; q < 16; ++q) removed |= swpart[q];
            int jbase = c * 64;
            int limit = PRE_NMS - jbase;
            u64 alive = ~removed;
            if (limit < 64) alive &= (1ull << limit) - 1ull;
            u64 mymask = (jbase + lane < PRE_NMS) ? sdiag[jbase + lane] : 0ull;
            while (alive && kept < NPROP) {
                int b = __ffsll((long long)alive) - 1;
                alive &= ~(1ull << b);
                u64 m = __shfl(mymask, b);
                if (lane == 0) skept[kept] = jbase + b;
                ++kept;
                alive &= ~m;
            }
            if (lane == 0) skcount = kept;
        }
        __syncthreads();
    }
    // ---- fused proposal writeout ----
    int keptFinal = skcount;
    for (int i = tid; i < NPROP * 4; i += 1024) {
        int p = i >> 2, d = i & 3;
        out2[i] = (p < keptFinal) ? props[(size_t)skept[p] * 4 + d] : 0.f;
    }
}

// ---------------------------------------------------------------------------
// ROI-align: 14x14 bilinear samples per proposal -> bf16 rois [1000][196*256]
// ---------------------------------------------------------------------------
__global__ __launch_bounds__(256) void roi_align_k(
    const float* __restrict__ X2, const float* __restrict__ boxes, u16* __restrict__ rois) {
    int p = blockIdx.x;
    int c = threadIdx.x;
    float y1 = boxes[p * 4], x1 = boxes[p * 4 + 1], y2 = boxes[p * 4 + 2], x2 = boxes[p * 4 + 3];
    for (int py = 0; py < 14; ++py) {
        float ty = (float)py / 13.0f;
        float ys = (y1 + ty * (y2 - y1)) * 63.0f;
        float fy = fminf(fmaxf(floorf(ys), 0.f), 62.f);
        int y0 = (int)fy;
        float wy = fminf(fmaxf(ys - fy, 0.f), 1.f);
        for (int px = 0; px < 14; ++px) {
            float tx = (float)px / 13.0f;
            float xs = (x1 + tx * (x2 - x1)) * 63.0f;
            float fx = fminf(fmaxf(floorf(xs), 0.f), 62.f);
            int x0 = (int)fx;
            float wx = fminf(fmaxf(xs - fx, 0.f), 1.f);
            const float* r0 = X2 + (size_t)((y0) * 64 + x0) * 256 + c;
            const float* r1 = r0 + 64 * 256;
            float v00 = r0[0], v01 = r0[256];
            float v10 = r1[0], v11 = r1[256];
            float top = v00 * (1.f - wx) + v01 * wx;
            float bot = v10 * (1.f - wx) + v11 * wx;
            float v = top * (1.f - wy) + bot * wy;
            rois[((size_t)p * 196 + py * 14 + px) * 256 + c] = f2bf(v);
        }
    }
}

// ---------------------------------------------------------------------------
// h1 GEMM: [1000][50176]bf16 @ [50176][1024]bf16 (B^T rows = out cols)
// 128x128 tile, BK=64, 4 waves x 64x64 quadrant, global_load_lds staging,
// T2 XOR-swizzle via pre-swizzled global source, T1 XCD-aware flat grid.
// ---------------------------------------------------------------------------
__global__ __launch_bounds__(256) void h1_gemm(
    const u16* __restrict__ Abf, const u16* __restrict__ Bbf, float* __restrict__ part) {
    const int tid = threadIdx.x;
    const int bid = blockIdx.x;
    const int ks = bid & 7;
    const int bm = ((bid >> 3) & 7) * 128;
    const int bn = (bid >> 6) * 128;
    __shared__ u16 As[128 * 64];
    __shared__ u16 Bs[128 * 64];
    const int wave = tid >> 6, lane = tid & 63;
    const size_t kbase = (size_t)ks * KCHUNK;
    const int wm = (wave >> 1) * 64, wn = (wave & 1) * 64;
    const int fr = lane & 15, fg = lane >> 4;
    const int srow = wave * 32 + (lane >> 3);
    const int scol = (((lane & 7) ^ (lane >> 3)) * 8);
    const size_t abase = (size_t)(bm + srow) * KROI + kbase + scol;
    const size_t bbase = (size_t)(bn + srow) * KROI + kbase + scol;
    u16* AsW = &As[wave * 2048];
    u16* BsW = &Bs[wave * 2048];

    f32x4 acc[4][4] = {};
    for (int k0 = 0; k0 < KCHUNK; k0 += 64) {
        __syncthreads();
#pragma unroll
        for (int i = 0; i < 4; ++i) {
            gload16(Abf + abase + (size_t)(i * 8) * KROI + k0, AsW + i * 512);
            gload16(Bbf + bbase + (size_t)(i * 8) * KROI + k0, BsW + i * 512);
        }
        __syncthreads();
        bf16x8 fa[4][2], fb[4][2];
#pragma unroll
        for (int t = 0; t < 4; ++t) {
#pragma unroll
            for (int s = 0; s < 2; ++s) {
                int ca = ((s * 4 + fg) ^ (fr & 7)) * 8;
                fa[t][s] = ldfrag(&As[(wm + t * 16 + fr) * 64 + ca]);
                fb[t][s] = ldfrag(&Bs[(wn + t * 16 + fr) * 64 + ca]);
            }
        }
#pragma unroll
        for (int s = 0; s < 2; ++s)
#pragma unroll
            for (int mi = 0; mi < 4; ++mi)
#pragma unroll
                for (int nj = 0; nj < 4; ++nj)
                    acc[mi][nj] = __builtin_amdgcn_mfma_f32_16x16x32_bf16(
                        fa[mi][s], fb[nj][s], acc[mi][nj], 0, 0, 0);
    }
    float* P = part + ((size_t)ks << 20);
#pragma unroll
    for (int mi = 0; mi < 4; ++mi) {
#pragma unroll
        for (int nj = 0; nj < 4; ++nj) {
            int r0 = bm + wm + mi * 16 + fg * 4;
            int c0 = bn + wn + nj * 16 + fr;
#pragma unroll
            for (int j = 0; j < 4; ++j)
                if (r0 + j < NPROP) P[(size_t)(r0 + j) * 1024 + c0] = acc[mi][nj][j];
        }
    }
}

__global__ __launch_bounds__(256) void reduce_h1(
    const float* __restrict__ part, const float* __restrict__ bias,
    const float* __restrict__ g, const float* __restrict__ be,
    const float* __restrict__ mu, const float* __restrict__ var, float* __restrict__ h1) {
    int i = blockIdx.x * 256 + threadIdx.x;
    if (i >= NPROP * 1024) return;
    int n = i & 1023, m = i >> 10;
    float s = 0.f;
#pragma unroll
    for (int k = 0; k < KSPLIT; ++k) s += part[((size_t)k << 20) + ((size_t)m << 10) + n];
    s += bias[n];
    float sc = g[n] / sqrtf(var[n] + BN_EPS);
    s = (s - mu[n]) * sc + be[n];
    h1[i] = fmaxf(s, 0.f);
}

// softmax over hroi[:, 0..80] (stride 512) -> out3 [1000][81]
__global__ __launch_bounds__(128) void softmax_cls(
    const float* __restrict__ hroi, float* __restrict__ out3) {
    __shared__ float sm[128];
    int row = blockIdx.x, t = threadIdx.x;
    float v = (t < 81) ? hroi[(size_t)row * 512 + t] : -1e30f;
    sm[t] = v;
    __syncthreads();
    for (int s = 64; s > 0; s >>= 1) {
        if (t < s) sm[t] = fmaxf(sm[t], sm[t + s]);
        __syncthreads();
    }
    float mx = sm[0];
    __syncthreads();
    float e = (t < 81) ? expf(v - mx) : 0.f;
    sm[t] = e;
    __syncthreads();
    for (int s = 64; s > 0; s >>= 1) {
        if (t < s) sm[t] += sm[t + s];
        __syncthreads();
    }
    float denom = sm[0];
    if (t < 81) out3[(size_t)row * 81 + t] = e / denom;
}

// ---------------------------------------------------------------------------
extern "C" void kernel_launch(void* const* d_in, const int* in_sizes, int n_in,
                              void* d_out, int out_size, void* d_ws, size_t ws_size,
                              hipStream_t stream) {
    const float* feature = (const float*)d_in[0];
    const float* w_fpn1 = (const float*)d_in[1];
    const float* b_fpn1 = (const float*)d_in[2];
    const float* w_fpn2 = (const float*)d_in[3];
    const float* b_fpn2 = (const float*)d_in[4];
    const float* w_rpn = (const float*)d_in[5];
    const float* b_rpn = (const float*)d_in[6];
    const float* w_cls = (const float*)d_in[7];
    const float* b_cls = (const float*)d_in[8];
    const float* w_dlt = (const float*)d_in[9];
    const float* b_dlt = (const float*)d_in[10];
    const float* w_rc1 = (const float*)d_in[11];
    const float* b_rc1 = (const float*)d_in[12];
    const float* g1 = (const float*)d_in[13];
    const float* be1 = (const float*)d_in[14];
    const float* m1 = (const float*)d_in[15];
    const float* v1 = (const float*)d_in[16];
    const float* w_rc2 = (const float*)d_in[17];
    const float* b_rc2 = (const float*)d_in[18];
    const float* g2 = (const float*)d_in[19];
    const float* be2 = (const float*)d_in[20];
    const float* m2 = (const float*)d_in[21];
    const float* v2 = (const float*)d_in[22];
    const float* w_log = (const float*)d_in[23];
    const float* b_log = (const float*)d_in[24];
    const float* w_bfc = (const float*)d_in[25];
    const float* b_bfc = (const float*)d_in[26];
    const int* image_h = (const int*)d_in[27];
    const int* image_w = (const int*)d_in[28];
    (void)in_sizes; (void)n_in; (void)out_size; (void)ws_size;

    float* out0 = (float*)d_out;          // rpn_probs  (36864,2)
    float* out1 = out0 + 73728;           // rpn_deltas (36864,4)
    float* out2 = out1 + 147456;          // proposals  (1000,4)
    float* out3 = out2 + 4000;            // cls_probs  (1000,81)
    float* out4 = out3 + 81000;           // box_deltas (1000,324)

    char* wsb = (char*)d_ws;
    size_t off = 0;
    auto take = [&](size_t b) -> void* {
        off = (off + 255) & ~(size_t)255;
        void* p = wsb + off;
        off += b;
        return p;
    };
    float* x1 = (float*)take((size_t)4096 * 256 * 4);
    float* x2 = (float*)take((size_t)4096 * 256 * 4);
    float* shr = (float*)take((size_t)4096 * 512 * 4);
    float* hcat = (float*)take((size_t)4096 * 64 * 4);
    float* wCat = (float*)take((size_t)512 * 64 * 4);
    float* bCat = (float*)take((size_t)64 * 4);
    float* wHead = (float*)take((size_t)1024 * 512 * 4);
    float* bHead = (float*)take((size_t)512 * 4);
    float* hroi = (float*)take((size_t)NPROP * 512 * 4);
    u64* keys = (u64*)take((size_t)NA * 8);
    u64* skeys = (u64*)take((size_t)PRE_NMS * 8);
    float* props = (float*)take((size_t)PRE_NMS * 4 * 4);
    u64* masksT = (u64*)take((size_t)MASKW * MASKT_STRIDE * 8);
    u64* diag = (u64*)take((size_t)PRE_NMS * 8);
    u16* rois = (u16*)take((size_t)NPROP * KROI * 2);
    u16* wT = (u16*)take((size_t)1024 * KROI * 2);
    float* part = (float*)take((size_t)KSPLIT * 1024 * 1024 * 4);  // 32 MB scratch
    float* h1 = (float*)take((size_t)NPROP * 1024 * 4);
    float* h2 = (float*)take((size_t)NPROP * 1024 * 4);

    // ---- RPN trunk (fp32, K-split + fused reduce epilogues) ----
    gemm_v3<false><<<dim3(32, 4, 8), 128, 0, stream>>>(feature, w_fpn1, part, 4096, 256, 1024, 128);
    reduce_part<0><<<dim3(1024), 256, 0, stream>>>(part, x1, 4096, 256, 8, b_fpn1, nullptr, nullptr, nullptr, nullptr);
    gemm_v3<true><<<dim3(32, 4, 8), 128, 0, stream>>>(x1, w_fpn2, part, 4096, 256, 2304, 288);
    reduce_part<0><<<dim3(1024), 256, 0, stream>>>(part, x2, 4096, 256, 8, b_fpn2, nullptr, nullptr, nullptr, nullptr);
    gemm_v3<true><<<dim3(32, 8, 4), 128, 0, stream>>>(x2, w_rpn, part, 4096, 512, 2304, 576);
    reduce_part<1><<<dim3(2048), 256, 0, stream>>>(part, shr, 4096, 512, 4, b_rpn, nullptr, nullptr, nullptr, nullptr);
    // merged cls+dlt heads: [4096][512] @ [512][64]
    pack_heads<<<dim3(128), 256, 0, stream>>>(w_cls, w_dlt, b_cls, b_dlt, wCat, bCat);
    gemm_v3<false><<<dim3(32, 1, 8), 128, 0, stream>>>(shr, wCat, part, 4096, 64, 512, 64);
    reduce_part<0><<<dim3(256), 256, 0, stream>>>(part, hcat, 4096, 64, 8, bCat, nullptr, nullptr, nullptr, nullptr);
    rpn_probs_keys<<<dim3(144), 256, 0, stream>>>(hcat, out0, out1, keys);

    // ---- top-6000 (exact lax.top_k order) + NMS ----
    radix_select_compact<<<1, 1024, 0, stream>>>(keys, skeys);
    rank_decode<<<dim3(24), 256, 0, stream>>>(skeys, out1, image_h, image_w, props);
    nms_masks<<<dim3(24, 94), 256, 0, stream>>>(props, masksT, diag);
    // greedy NMS + proposal writeout (block 0) + w_rc1 bf16-transpose (blocks 1..)
    nms_greedy_conv<<<dim3(1 + CONV_TILES), 1024, 0, stream>>>(masksT, diag, props, out2, w_rc1, wT);

    // ---- ROI head ----
    roi_align_k<<<dim3(1000), 256, 0, stream>>>(x2, out2, rois);
    h1_gemm<<<dim3(512), 256, 0, stream>>>(rois, wT, part);
    reduce_h1<<<dim3(4000), 256, 0, stream>>>(part, b_rc1, g1, be1, m1, v1, h1);
    gemm_v3<false><<<dim3(8, 16, 2), 128, 0, stream>>>(h1, w_rc2, part, 1000, 1024, 1024, 512);
    reduce_part<2><<<dim3(1000), 256, 0, stream>>>(part, h2, 1000, 1024, 2, b_rc2, g2, be2, m2, v2);
    // merged cls-logits + box heads: [1000][1024] @ [1024][512]
    pack_roi_heads<<<dim3(2048), 256, 0, stream>>>(w_log, w_bfc, b_log, b_bfc, wHead, bHead);
    gemm_v3<false><<<dim3(8, 8, 2), 128, 0, stream>>>(h2, wHead, part, 1000, 512, 1024, 512);
    reduce_part<0><<<dim3(500), 256, 0, stream>>>(part, hroi, 1000, 512, 2, bHead, nullptr, nullptr, nullptr, nullptr);
    split_roi<<<dim3(1266), 256, 0, stream>>>(hroi, out4);
    softmax_cls<<<dim3(1000), 128, 0, stream>>>(hroi, out3);
}

// Round 16
// 1013.875 us; speedup vs baseline: 1.0217x; 1.0217x over previous
//
#include <hip/hip_runtime.h>
#include <hip/hip_bf16.h>

typedef unsigned int u32;
typedef unsigned long long u64;
typedef unsigned short u16;

typedef float f32x4 __attribute__((ext_vector_type(4)));
typedef __bf16 bf16x8 __attribute__((ext_vector_type(8)));
typedef unsigned short u16x8 __attribute__((ext_vector_type(8)));
typedef unsigned short u16x4 __attribute__((ext_vector_type(4)));

#define NA 36864          // 64*64*9 anchors
#define PRE_NMS 6000
#define NPROP 1000
#define KROI 50176        // 14*14*256
#define MASKW 94          // ceil(6000/64)
#define MASKT_STRIDE 6144 // padded row stride of transposed mask
#define KSPLIT 8
#define KCHUNK (KROI / KSPLIT)  // 6272
#define BN_EPS 1e-3f
#define CONV_TILES 3136   // 196 k-groups (4x64 rows each) x 16 n-tiles of w_rc1

__device__ __forceinline__ u16 f2bf(float v) {
    __bf16 h = (__bf16)v;
    return __builtin_bit_cast(u16, h);
}
__device__ __forceinline__ bf16x8 ldfrag(const u16* p) {
    return __builtin_bit_cast(bf16x8, *(const u16x8*)p);
}
__device__ __forceinline__ void gload16(const void* g, void* l) {
    __builtin_amdgcn_global_load_lds(
        (const __attribute__((address_space(1))) unsigned int*)g,
        (__attribute__((address_space(3))) unsigned int*)l, 16, 0, 0);
}

// ---------------------------------------------------------------------------
// gemm_v3: fp32 partial GEMM. part[ks] = A[M][kchunk-slice] @ B[.][N].
// 128x64 tile, 128 threads, 8x8 per thread, double-buffered LDS.
// Structural ceiling ~50% VALUBusy (LDS-instruction-bound): gemm_v4 spilled,
// deeper K-split (R12) was occupancy-neutral. Do not re-attempt.
// CONV3: A is implicit im2col of X[64][64][256], 3x3 SAME (K = 2304).
// ---------------------------------------------------------------------------
template <bool CONV3>
__global__ __launch_bounds__(128) void gemm_v3(
    const float* __restrict__ A, const float* __restrict__ B, float* __restrict__ part,
    int M, int N, int K, int kchunk) {
    __shared__ float As[2][16][132];
    __shared__ float Bs[2][16][68];
    const int tid = threadIdx.x;
    const int bm = blockIdx.x * 128, bn = blockIdx.y * 64;
    const int ks = blockIdx.z;
    const int kbeg = ks * kchunk, kend = kbeg + kchunk;
    const int tx = tid & 7, ty = tid >> 3;
    (void)K;

    float4 ra[4], rb[2];
    auto loadA = [&](int k0, int i) -> float4 {
        int e = tid + 128 * i;  // 0..511
        int m = e >> 2, kq = (e & 3) * 4;
        float4 v = {0.f, 0.f, 0.f, 0.f};
        int gm = bm + m;
        if (CONV3) {
            int gg = k0 >> 8;
            int dy = gg / 3, dx = gg - 3 * dy;
            int pr = gm >> 6, pc = gm & 63;
            int sr = pr + dy - 1, sc = pc + dx - 1;
            int ch = (k0 & 255) + kq;
            if (sr >= 0 && sr < 64 && sc >= 0 && sc < 64)
                v = *(const float4*)&A[(size_t)((sr << 6) + sc) * 256 + ch];
        } else {
            if (gm < M) v = *(const float4*)&A[(size_t)gm * K + k0 + kq];
        }
        return v;
    };
    auto loadB = [&](int k0, int i) -> float4 {
        int e = tid + 128 * i;  // 0..255
        int n4 = (e & 15) * 4, kk = e >> 4;
        return *(const float4*)&B[(size_t)(k0 + kk) * N + bn + n4];
    };
    auto stage = [&](int s) {
#pragma unroll
        for (int i = 0; i < 4; ++i) {
            int e = tid + 128 * i; int m = e >> 2, kq = (e & 3) * 4;
            As[s][kq + 0][m] = ra[i].x; As[s][kq + 1][m] = ra[i].y;
            As[s][kq + 2][m] = ra[i].z; As[s][kq + 3][m] = ra[i].w;
        }
#pragma unroll
        for (int i = 0; i < 2; ++i) {
            int e = tid + 128 * i; int n4 = (e & 15) * 4, kk = e >> 4;
            *(float4*)&Bs[s][kk][n4] = rb[i];
        }
    };

    float acc[8][8] = {};
#pragma unroll
    for (int i = 0; i < 4; ++i) ra[i] = loadA(kbeg, i);
#pragma unroll
    for (int i = 0; i < 2; ++i) rb[i] = loadB(kbeg, i);
    stage(0);
    if (kbeg + 16 < kend) {
#pragma unroll
        for (int i = 0; i < 4; ++i) ra[i] = loadA(kbeg + 16, i);
#pragma unroll
        for (int i = 0; i < 2; ++i) rb[i] = loadB(kbeg + 16, i);
    }
    __syncthreads();
    int s = 0;
    for (int k0 = kbeg; k0 < kend; k0 += 16) {
        if (k0 + 16 < kend) {
            stage(s ^ 1);
            if (k0 + 32 < kend) {
#pragma unroll
                for (int i = 0; i < 4; ++i) ra[i] = loadA(k0 + 32, i);
#pragma unroll
                for (int i = 0; i < 2; ++i) rb[i] = loadB(k0 + 32, i);
            }
        }
#pragma unroll
        for (int kk = 0; kk < 16; ++kk) {
            float4 a0 = *(const float4*)&As[s][kk][8 * ty];
            float4 a1 = *(const float4*)&As[s][kk][8 * ty + 4];
            float4 b0 = *(const float4*)&Bs[s][kk][8 * tx];
            float4 b1 = *(const float4*)&Bs[s][kk][8 * tx + 4];
            const float av[8] = {a0.x, a0.y, a0.z, a0.w, a1.x, a1.y, a1.z, a1.w};
            const float bv[8] = {b0.x, b0.y, b0.z, b0.w, b1.x, b1.y, b1.z, b1.w};
#pragma unroll
            for (int r = 0; r < 8; ++r)
#pragma unroll
                for (int c = 0; c < 8; ++c) acc[r][c] = fmaf(av[r], bv[c], acc[r][c]);
        }
        __syncthreads();
        s ^= 1;
    }
    float* P = part + (size_t)ks * ((size_t)M * N);
#pragma unroll
    for (int r = 0; r < 8; ++r) {
        int gm = bm + 8 * ty + r;
        if (gm >= M) continue;
        *(float4*)&P[(size_t)gm * N + bn + 8 * tx] = *(const float4*)&acc[r][0];
        *(float4*)&P[(size_t)gm * N + bn + 8 * tx + 4] = *(const float4*)&acc[r][4];
    }
}

// ---------------------------------------------------------------------------
// reduce K-split partials + bias + epilogue. EPI: 0 none, 1 relu, 2 bn+relu.
// ---------------------------------------------------------------------------
template <int EPI>
__global__ __launch_bounds__(256) void reduce_part(
    const float* __restrict__ part, float* __restrict__ C, int M, int N, int KS,
    const float* __restrict__ bias, const float* __restrict__ g,
    const float* __restrict__ be, const float* __restrict__ mu,
    const float* __restrict__ var) {
    int i = blockIdx.x * 256 + threadIdx.x;
    int total = (M * N) >> 2;
    if (i >= total) return;
    size_t off = (size_t)i * 4;
    int n = (int)(off % (size_t)N);
    size_t slice = (size_t)M * N;
    float4 sv = {0.f, 0.f, 0.f, 0.f};
    for (int k = 0; k < KS; ++k) {
        float4 v = *(const float4*)&part[(size_t)k * slice + off];
        sv.x += v.x; sv.y += v.y; sv.z += v.z; sv.w += v.w;
    }
    float o[4] = {sv.x, sv.y, sv.z, sv.w};
#pragma unroll
    for (int j = 0; j < 4; ++j) {
        float v = o[j] + bias[n + j];
        if constexpr (EPI == 1) v = fmaxf(v, 0.f);
        if constexpr (EPI == 2) {
            float sc = g[n + j] / sqrtf(var[n + j] + BN_EPS);
            v = (v - mu[n + j]) * sc + be[n + j];
            v = fmaxf(v, 0.f);
        }
        o[j] = v;
    }
    *(float4*)&C[off] = *(const float4*)&o[0];
}

// pack w_cls [512][18] + w_dlt [512][36] -> wCat [512][64] (zero pad), bCat[64]
__global__ __launch_bounds__(256) void pack_heads(
    const float* __restrict__ wc, const float* __restrict__ wd,
    const float* __restrict__ bc, const float* __restrict__ bd,
    float* __restrict__ wCat, float* __restrict__ bCat) {
    int i = blockIdx.x * 256 + threadIdx.x;
    if (i < 512 * 64) {
        int k = i >> 6, n = i & 63;
        float v = 0.f;
        if (n < 18) v = wc[k * 18 + n];
        else if (n < 54) v = wd[k * 36 + (n - 18)];
        wCat[i] = v;
    }
    if (i < 64) bCat[i] = (i < 18) ? bc[i] : ((i < 54) ? bd[i - 18] : 0.f);
}

// pack w_log [1024][81] + w_bfc [1024][324] -> wHead [1024][512] (pad), bHead[512]
__global__ __launch_bounds__(256) void pack_roi_heads(
    const float* __restrict__ wl, const float* __restrict__ wb,
    const float* __restrict__ bl, const float* __restrict__ bb,
    float* __restrict__ wH, float* __restrict__ bH) {
    int i = blockIdx.x * 256 + threadIdx.x;
    if (i < 1024 * 512) {
        int k = i >> 9, n = i & 511;
        float v = 0.f;
        if (n < 81) v = wl[k * 81 + n];
        else if (n < 405) v = wb[k * 324 + (n - 81)];
        wH[i] = v;
    }
    if (i < 512) bH[i] = (i < 81) ? bl[i] : ((i < 405) ? bb[i - 81] : 0.f);
}

// hroi [1000][512] cols 81..404 -> out4 [1000][324]
__global__ __launch_bounds__(256) void split_roi(
    const float* __restrict__ hr, float* __restrict__ out4) {
    int i = blockIdx.x * 256 + threadIdx.x;
    if (i >= NPROP * 324) return;
    int r = i / 324, c = i - r * 324;
    out4[i] = hr[r * 512 + 81 + c];
}

// ---------------------------------------------------------------------------
// RPN softmax pair + delta copy (from hcat [4096][64]) -> out0, out1, keys
// ---------------------------------------------------------------------------
__global__ __launch_bounds__(256) void rpn_probs_keys(
    const float* __restrict__ hc, float* __restrict__ out0, float* __restrict__ out1,
    u64* __restrict__ keys) {
    int i = blockIdx.x * 256 + threadIdx.x;
    if (i >= NA) return;
    int cell = i / 9, a = i - cell * 9;
    const float* row = &hc[cell * 64];
    float l0 = row[2 * a], l1 = row[2 * a + 1];
    float m = fmaxf(l0, l1);
    float e0 = expf(l0 - m), e1 = expf(l1 - m);
    float ssum = e0 + e1;
    float p0 = e0 / ssum, p1 = e1 / ssum;
    out0[2 * i] = p0;
    out0[2 * i + 1] = p1;
    keys[i] = ((u64)__float_as_uint(p1) << 32) | (u64)(0xFFFFFFFFu - (u32)i);
    const float* src = row + 18 + 4 * a;
    float4 d = {src[0], src[1], src[2], src[3]};
    *(float4*)&out1[(size_t)i * 4] = d;
}

// ---------------------------------------------------------------------------
// Exact 6000-th largest key via 8-pass MSB radix select, then compact the
// 6000 qualifying keys into skeys (fused; single block, 1024 threads).
// ---------------------------------------------------------------------------
__global__ __launch_bounds__(1024) void radix_select_compact(
    const u64* __restrict__ keys, u64* __restrict__ skeys) {
    __shared__ u32 hist[256];
    __shared__ u64 sPrefix, sMask;
    __shared__ int sRank;
    __shared__ u32 sCount;
    int tid = threadIdx.x;
    if (tid == 0) { sPrefix = 0; sMask = 0; sRank = PRE_NMS; sCount = 0; }
    __syncthreads();
    for (int p = 56; p >= 0; p -= 8) {
        if (tid < 256) hist[tid] = 0;
        __syncthreads();
        u64 pref = sPrefix, msk = sMask;
        for (int i = tid; i < NA; i += 1024) {
            u64 k = keys[i];
            if ((k & msk) == pref) atomicAdd(&hist[(u32)((k >> p) & 255)], 1u);
        }
        __syncthreads();
        if (tid == 0) {
            int cum = 0, rank = sRank, sel = 0;
            for (int d = 255; d >= 0; --d) {
                int c = (int)hist[d];
                if (cum + c >= rank) { sel = d; sRank = rank - cum; break; }
                cum += c;
            }
            sPrefix = pref | ((u64)(u32)sel << p);
            sMask = msk | (0xFFull << p);
        }
        __syncthreads();
    }
    u64 thr = sPrefix;
    for (int i = tid; i < NA; i += 1024) {
        u64 k = keys[i];
        if (k >= thr) {
            u32 pos = atomicAdd(&sCount, 1u);
            skeys[pos] = k;
        }
    }
}

// ---------------------------------------------------------------------------
// Fused rank-sort + decode: exact descending rank by LDS counting (keys
// unique), decode box, write props[rank] directly.
// ---------------------------------------------------------------------------
__global__ __launch_bounds__(256) void rank_decode(
    const u64* __restrict__ skeys, const float* __restrict__ deltas,
    const int* __restrict__ ih, const int* __restrict__ iw, float* __restrict__ props) {
    __shared__ u64 lds[PRE_NMS];
    const int tid = threadIdx.x;
    for (int i = tid; i < PRE_NMS; i += 256) lds[i] = skeys[i];
    __syncthreads();
    int i = blockIdx.x * 256 + tid;
    if (i >= PRE_NMS) return;
    u64 k = lds[i];
    int c = 0;
#pragma unroll 4
    for (int j = 0; j < PRE_NMS; ++j) c += (lds[j] > k) ? 1 : 0;
    u32 idx = 0xFFFFFFFFu - (u32)(k & 0xFFFFFFFFull);
    float H = (float)(*ih), W = (float)(*iw);
    int a = idx % 9;
    int cell = idx / 9;
    int r = cell >> 6, cc = cell & 63;
    float sy = H / 64.0f, sx = W / 64.0f;
    float cy = ((float)r + 0.5f) * sy, cx = ((float)cc + 0.5f) * sx;
    const float scales[3] = {64.f, 128.f, 256.f};
    const float ratios[3] = {0.5f, 1.f, 2.f};
    float sq = sqrtf(ratios[a % 3]);
    float scl = scales[a / 3];
    float ah = scl * sq, aw = scl / sq;
    float ay1 = cy - ah * 0.5f, ax1 = cx - aw * 0.5f;
    float h = ah, w = aw;
    float d0 = deltas[(size_t)idx * 4 + 0], d1 = deltas[(size_t)idx * 4 + 1];
    float d2 = deltas[(size_t)idx * 4 + 2], d3 = deltas[(size_t)idx * 4 + 3];
    float ncy = ay1 + 0.5f * h + d0 * h;
    float ncx = ax1 + 0.5f * w + d1 * w;
    float nh = h * expf(d2), nw = w * expf(d3);
    float y1 = ncy - 0.5f * nh, x1 = ncx - 0.5f * nw;
    float y2 = ncy + 0.5f * nh, x2 = ncx + 0.5f * nw;
    float4 box = {fminf(fmaxf(y1, 0.f), H) / H, fminf(fmaxf(x1, 0.f), W) / W,
                  fminf(fmaxf(y2, 0.f), H) / H, fminf(fmaxf(x2, 0.f), W) / W};
    *(float4*)&props[(size_t)c * 4] = box;
}

// ---------------------------------------------------------------------------
// NMS: transposed pairwise suppression bitmask + diag words.
// Chunk (j) boxes staged once per block in LDS; inner loop is LDS broadcast.
// ---------------------------------------------------------------------------
__global__ __launch_bounds__(256) void nms_masks(
    const float* __restrict__ props, u64* __restrict__ masksT, u64* __restrict__ diag) {
    __shared__ float4 chunk[64];
    int tid = threadIdx.x;
    int i = blockIdx.x * 256 + tid;
    int w = blockIdx.y;
    int jbase = w * 64;
    if (tid < 64 && jbase + tid < PRE_NMS)
        chunk[tid] = *(const float4*)&props[(size_t)(jbase + tid) * 4];
    __syncthreads();
    if (i >= PRE_NMS) return;
    float4 bi = *(const float4*)&props[(size_t)i * 4];
    float y1 = bi.x, x1 = bi.y, y2 = bi.z, x2 = bi.w;
    float ai = (y2 - y1) * (x2 - x1);
    u64 bits = 0;
    int lim = PRE_NMS - jbase; if (lim > 64) lim = 64;
    for (int b = 0; b < lim; ++b) {
        float4 bj = chunk[b];
        float iy1 = fmaxf(y1, bj.x), ix1 = fmaxf(x1, bj.y);
        float iy2 = fminf(y2, bj.z), ix2 = fminf(x2, bj.w);
        float inter = fmaxf(iy2 - iy1, 0.f) * fmaxf(ix2 - ix1, 0.f);
        float aj = (bj.z - bj.x) * (bj.w - bj.y);
        float iou = inter / (ai + aj - inter + 1e-8f);
        if (iou > 0.7f) bits |= (1ull << b);
    }
    masksT[(size_t)w * MASKT_STRIDE + i] = bits;
    if (w == (i >> 6)) diag[i] = bits;
}

// ---------------------------------------------------------------------------
// Fused: block 0 = PIPELINED lazy greedy NMS + proposal writeout;
// blocks 1.. = w_rc1 -> bf16^T (4 k-tiles/block).
// Pipeline: during chunk c, waves 1-14 gather removed-partials for chunk c+1
// over the stable skept[0..sBase) snapshot, wave 15 prefetches
// masksT[c+1][boxes of chunk c], wave 0 resolves chunk c. Chunk c's new kept
// contributions to removed[c+1] come from the prefetched rows masked by
// wave 0's keptbits register (OR-idempotent split == exact greedy).
// ---------------------------------------------------------------------------
__global__ __launch_bounds__(1024) void nms_greedy_conv(
    const u64* __restrict__ masksT, const u64* __restrict__ diag,
    const float* __restrict__ props, float* __restrict__ out2,
    const float* __restrict__ Wf, u16* __restrict__ WT) {
    __shared__ u64 sdiag[PRE_NMS];
    __shared__ int skept[NPROP];
    __shared__ u64 sG[2][16];   // gather partials (slots 1..14), parity by chunk
    __shared__ u64 sP[2][64];   // prefetched next-word rows of current chunk's boxes
    __shared__ int sBase;       // kept count at entry of current chunk
    const int tid = threadIdx.x;

    if (blockIdx.x != 0) {
        // ---- conversion role: 4 consecutive 64-row k-tiles x one n-tile ----
        u16* tile = (u16*)sdiag;  // [4][64][68] u16 = 34816 B alias
        int bid = blockIdx.x - 1;
        int kg = bid % 196, n0 = (bid / 196) * 64;
        int k0 = kg * 256;
        int kk = tid >> 4, n4 = (tid & 15) * 4;
        float4 v[4];
#pragma unroll
        for (int t = 0; t < 4; ++t)
            v[t] = *(const float4*)&Wf[(size_t)(k0 + t * 64 + kk) * 1024 + n0 + n4];
#pragma unroll
        for (int t = 0; t < 4; ++t) {
            u16* tt = tile + t * 64 * 68;
            tt[(n4 + 0) * 68 + kk] = f2bf(v[t].x);
            tt[(n4 + 1) * 68 + kk] = f2bf(v[t].y);
            tt[(n4 + 2) * 68 + kk] = f2bf(v[t].z);
            tt[(n4 + 3) * 68 + kk] = f2bf(v[t].w);
        }
        __syncthreads();
        int nn = tid >> 4, k4 = (tid & 15) * 4;
#pragma unroll
        for (int t = 0; t < 4; ++t) {
            u16x4 o = *(const u16x4*)&tile[(t * 64 + nn) * 68 + k4];
            *(u16x4*)&WT[(size_t)(n0 + nn) * KROI + k0 + t * 64 + k4] = o;
        }
        return;
    }

    // ---- pipelined greedy role (block 0) ----
    const int lane = tid & 63;
    const int wid = tid >> 6;
    for (int i = tid; i < PRE_NMS; i += 1024) sdiag[i] = diag[i];
    if (tid < 16) { sG[0][tid] = 0; sG[1][tid] = 0; }
    if (tid < 64) { sP[0][tid] = 0; sP[1][tid] = 0; }
    if (tid == 0) sBase = 0;
    __syncthreads();

    int kept = 0;        // wave 0 register state
    u64 kbPrev = 0;      // keptbits of previous chunk (wave 0)
    for (int c = 0; c < MASKW; ++c) {
        const int p = c & 1, q = p ^ 1;
        int base = sBase;          // stable: written before previous barrier
        if (base >= NPROP) break;

        if (wid >= 1 && wid <= 14) {
            // gather removed-partials for chunk c+1 over kept[0..base)
            u64 acc = 0;
            if (c + 1 < MASKW) {
                const u64* mrowN = masksT + (size_t)(c + 1) * MASKT_STRIDE;
                for (int t = (wid - 1) * 64 + lane; t < base; t += 896)
                    acc |= mrowN[skept[t]];
            }
#pragma unroll
            for (int s = 32; s > 0; s >>= 1) acc |= __shfl_xor(acc, s);
            if (lane == 0) sG[q][wid] = acc;
        } else if (wid == 15) {
            // prefetch masksT[c+1][boxes of chunk c]
            u64 v = 0;
            int jb = c * 64;
            if (c + 1 < MASKW && jb + lane < PRE_NMS)
                v = masksT[(size_t)(c + 1) * MASKT_STRIDE + jb + lane];
            sP[q][lane] = v;
        } else {
            // wave 0: removed[c] = OR(sG[p][1..14]) | OR_{b in kbPrev} sP[p][b]
            u64 contrib = ((kbPrev >> lane) & 1ull) ? sP[p][lane] : 0ull;
            if (lane >= 1 && lane <= 14) contrib |= sG[p][lane];
#pragma unroll
            for (int s = 32; s > 0; s >>= 1) contrib |= __shfl_xor(contrib, s);
            u64 removed = contrib;
            int jbase = c * 64;
            int limit = PRE_NMS - jbase;
            u64 alive = ~removed;
            if (limit < 64) alive &= (1ull << limit) - 1ull;
            u64 mymask = (jbase + lane < PRE_NMS) ? sdiag[jbase + lane] : 0ull;
            u64 kb = 0;
            while (alive && kept < NPROP) {
                int b = __ffsll((long long)alive) - 1;
                alive &= ~(1ull << b);
                u64 m = __shfl(mymask, b);
                if (lane == 0) skept[kept] = jbase + b;
                ++kept;
                kb |= (1ull << b);
                alive &= ~m;
            }
            kbPrev = kb;
            if (lane == 0) sBase = kept;
        }
        __syncthreads();
    }
    // ---- fused proposal writeout ----
    int keptFinal = sBase;
    for (int i = tid; i < NPROP * 4; i += 1024) {
        int pp = i >> 2, d = i & 3;
        out2[i] = (pp < keptFinal) ? props[(size_t)skept[pp] * 4 + d] : 0.f;
    }
}

// ---------------------------------------------------------------------------
// ROI-align: 14x14 bilinear samples per proposal -> bf16 rois [1000][196*256]
// ---------------------------------------------------------------------------
__global__ __launch_bounds__(256) void roi_align_k(
    const float* __restrict__ X2, const float* __restrict__ boxes, u16* __restrict__ rois) {
    int p = blockIdx.x;
    int c = threadIdx.x;
    float y1 = boxes[p * 4], x1 = boxes[p * 4 + 1], y2 = boxes[p * 4 + 2], x2 = boxes[p * 4 + 3];
    for (int py = 0; py < 14; ++py) {
        float ty = (float)py / 13.0f;
        float ys = (y1 + ty * (y2 - y1)) * 63.0f;
        float fy = fminf(fmaxf(floorf(ys), 0.f), 62.f);
        int y0 = (int)fy;
        float wy = fminf(fmaxf(ys - fy, 0.f), 1.f);
        for (int px = 0; px < 14; ++px) {
            float tx = (float)px / 13.0f;
            float xs = (x1 + tx * (x2 - x1)) * 63.0f;
            float fx = fminf(fmaxf(floorf(xs), 0.f), 62.f);
            int x0 = (int)fx;
            float wx = fminf(fmaxf(xs - fx, 0.f), 1.f);
            const float* r0 = X2 + (size_t)((y0) * 64 + x0) * 256 + c;
            const float* r1 = r0 + 64 * 256;
            float v00 = r0[0], v01 = r0[256];
            float v10 = r1[0], v11 = r1[256];
            float top = v00 * (1.f - wx) + v01 * wx;
            float bot = v10 * (1.f - wx) + v11 * wx;
            float v = top * (1.f - wy) + bot * wy;
            rois[((size_t)p * 196 + py * 14 + px) * 256 + c] = f2bf(v);
        }
    }
}

// ---------------------------------------------------------------------------
// h1 GEMM: [1000][50176]bf16 @ [50176][1024]bf16 (B^T rows = out cols)
// 128x128 tile, BK=64, 4 waves x 64x64 quadrant, global_load_lds staging,
// T2 XOR-swizzle via pre-swizzled global source, T1 XCD-aware flat grid.
// ---------------------------------------------------------------------------
__global__ __launch_bounds__(256) void h1_gemm(
    const u16* __restrict__ Abf, const u16* __restrict__ Bbf, float* __restrict__ part) {
    const int tid = threadIdx.x;
    const int bid = blockIdx.x;
    const int ks = bid & 7;
    const int bm = ((bid >> 3) & 7) * 128;
    const int bn = (bid >> 6) * 128;
    __shared__ u16 As[128 * 64];
    __shared__ u16 Bs[128 * 64];
    const int wave = tid >> 6, lane = tid & 63;
    const size_t kbase = (size_t)ks * KCHUNK;
    const int wm = (wave >> 1) * 64, wn = (wave & 1) * 64;
    const int fr = lane & 15, fg = lane >> 4;
    const int srow = wave * 32 + (lane >> 3);
    const int scol = (((lane & 7) ^ (lane >> 3)) * 8);
    const size_t abase = (size_t)(bm + srow) * KROI + kbase + scol;
    const size_t bbase = (size_t)(bn + srow) * KROI + kbase + scol;
    u16* AsW = &As[wave * 2048];
    u16* BsW = &Bs[wave * 2048];

    f32x4 acc[4][4] = {};
    for (int k0 = 0; k0 < KCHUNK; k0 += 64) {
        __syncthreads();
#pragma unroll
        for (int i = 0; i < 4; ++i) {
            gload16(Abf + abase + (size_t)(i * 8) * KROI + k0, AsW + i * 512);
            gload16(Bbf + bbase + (size_t)(i * 8) * KROI + k0, BsW + i * 512);
        }
        __syncthreads();
        bf16x8 fa[4][2], fb[4][2];
#pragma unroll
        for (int t = 0; t < 4; ++t) {
#pragma unroll
            for (int s = 0; s < 2; ++s) {
                int ca = ((s * 4 + fg) ^ (fr & 7)) * 8;
                fa[t][s] = ldfrag(&As[(wm + t * 16 + fr) * 64 + ca]);
                fb[t][s] = ldfrag(&Bs[(wn + t * 16 + fr) * 64 + ca]);
            }
        }
#pragma unroll
        for (int s = 0; s < 2; ++s)
#pragma unroll
            for (int mi = 0; mi < 4; ++mi)
#pragma unroll
                for (int nj = 0; nj < 4; ++nj)
                    acc[mi][nj] = __builtin_amdgcn_mfma_f32_16x16x32_bf16(
                        fa[mi][s], fb[nj][s], acc[mi][nj], 0, 0, 0);
    }
    float* P = part + ((size_t)ks << 20);
#pragma unroll
    for (int mi = 0; mi < 4; ++mi) {
#pragma unroll
        for (int nj = 0; nj < 4; ++nj) {
            int r0 = bm + wm + mi * 16 + fg * 4;
            int c0 = bn + wn + nj * 16 + fr;
#pragma unroll
            for (int j = 0; j < 4; ++j)
                if (r0 + j < NPROP) P[(size_t)(r0 + j) * 1024 + c0] = acc[mi][nj][j];
        }
    }
}

__global__ __launch_bounds__(256) void reduce_h1(
    const float* __restrict__ part, const float* __restrict__ bias,
    const float* __restrict__ g, const float* __restrict__ be,
    const float* __restrict__ mu, const float* __restrict__ var, float* __restrict__ h1) {
    int i = blockIdx.x * 256 + threadIdx.x;
    if (i >= NPROP * 1024) return;
    int n = i & 1023, m = i >> 10;
    float s = 0.f;
#pragma unroll
    for (int k = 0; k < KSPLIT; ++k) s += part[((size_t)k << 20) + ((size_t)m << 10) + n];
    s += bias[n];
    float sc = g[n] / sqrtf(var[n] + BN_EPS);
    s = (s - mu[n]) * sc + be[n];
    h1[i] = fmaxf(s, 0.f);
}

// softmax over hroi[:, 0..80] (stride 512) -> out3 [1000][81]
__global__ __launch_bounds__(128) void softmax_cls(
    const float* __restrict__ hroi, float* __restrict__ out3) {
    __shared__ float sm[128];
    int row = blockIdx.x, t = threadIdx.x;
    float v = (t < 81) ? hroi[(size_t)row * 512 + t] : -1e30f;
    sm[t] = v;
    __syncthreads();
    for (int s = 64; s > 0; s >>= 1) {
        if (t < s) sm[t] = fmaxf(sm[t], sm[t + s]);
        __syncthreads();
    }
    float mx = sm[0];
    __syncthreads();
    float e = (t < 81) ? expf(v - mx) : 0.f;
    sm[t] = e;
    __syncthreads();
    for (int s = 64; s > 0; s >>= 1) {
        if (t < s) sm[t] += sm[t + s];
        __syncthreads();
    }
    float denom = sm[0];
    if (t < 81) out3[(size_t)row * 81 + t] = e / denom;
}

// ---------------------------------------------------------------------------
extern "C" void kernel_launch(void* const* d_in, const int* in_sizes, int n_in,
                              void* d_out, int out_size, void* d_ws, size_t ws_size,
                              hipStream_t stream) {
    const float* feature = (const float*)d_in[0];
    const float* w_fpn1 = (const float*)d_in[1];
    const float* b_fpn1 = (const float*)d_in[2];
    const float* w_fpn2 = (const float*)d_in[3];
    const float* b_fpn2 = (const float*)d_in[4];
    const float* w_rpn = (const float*)d_in[5];
    const float* b_rpn = (const float*)d_in[6];
    const float* w_cls = (const float*)d_in[7];
    const float* b_cls = (const float*)d_in[8];
    const float* w_dlt = (const float*)d_in[9];
    const float* b_dlt = (const float*)d_in[10];
    const float* w_rc1 = (const float*)d_in[11];
    const float* b_rc1 = (const float*)d_in[12];
    const float* g1 = (const float*)d_in[13];
    const float* be1 = (const float*)d_in[14];
    const float* m1 = (const float*)d_in[15];
    const float* v1 = (const float*)d_in[16];
    const float* w_rc2 = (const float*)d_in[17];
    const float* b_rc2 = (const float*)d_in[18];
    const float* g2 = (const float*)d_in[19];
    const float* be2 = (const float*)d_in[20];
    const float* m2 = (const float*)d_in[21];
    const float* v2 = (const float*)d_in[22];
    const float* w_log = (const float*)d_in[23];
    const float* b_log = (const float*)d_in[24];
    const float* w_bfc = (const float*)d_in[25];
    const float* b_bfc = (const float*)d_in[26];
    const int* image_h = (const int*)d_in[27];
    const int* image_w = (const int*)d_in[28];
    (void)in_sizes; (void)n_in; (void)out_size; (void)ws_size;

    float* out0 = (float*)d_out;          // rpn_probs  (36864,2)
    float* out1 = out0 + 73728;           // rpn_deltas (36864,4)
    float* out2 = out1 + 147456;          // proposals  (1000,4)
    float* out3 = out2 + 4000;            // cls_probs  (1000,81)
    float* out4 = out3 + 81000;           // box_deltas (1000,324)

    char* wsb = (char*)d_ws;
    size_t off = 0;
    auto take = [&](size_t b) -> void* {
        off = (off + 255) & ~(size_t)255;
        void* p = wsb + off;
        off += b;
        return p;
    };
    float* x1 = (float*)take((size_t)4096 * 256 * 4);
    float* x2 = (float*)take((size_t)4096 * 256 * 4);
    float* shr = (float*)take((size_t)4096 * 512 * 4);
    float* hcat = (float*)take((size_t)4096 * 64 * 4);
    float* wCat = (float*)take((size_t)512 * 64 * 4);
    float* bCat = (float*)take((size_t)64 * 4);
    float* wHead = (float*)take((size_t)1024 * 512 * 4);
    float* bHead = (float*)take((size_t)512 * 4);
    float* hroi = (float*)take((size_t)NPROP * 512 * 4);
    u64* keys = (u64*)take((size_t)NA * 8);
    u64* skeys = (u64*)take((size_t)PRE_NMS * 8);
    float* props = (float*)take((size_t)PRE_NMS * 4 * 4);
    u64* masksT = (u64*)take((size_t)MASKW * MASKT_STRIDE * 8);
    u64* diag = (u64*)take((size_t)PRE_NMS * 8);
    u16* rois = (u16*)take((size_t)NPROP * KROI * 2);
    u16* wT = (u16*)take((size_t)1024 * KROI * 2);
    float* part = (float*)take((size_t)KSPLIT * 1024 * 1024 * 4);  // 32 MB scratch
    float* h1 = (float*)take((size_t)NPROP * 1024 * 4);
    float* h2 = (float*)take((size_t)NPROP * 1024 * 4);

    // ---- RPN trunk (fp32, K-split + fused reduce epilogues) ----
    gemm_v3<false><<<dim3(32, 4, 8), 128, 0, stream>>>(feature, w_fpn1, part, 4096, 256, 1024, 128);
    reduce_part<0><<<dim3(1024), 256, 0, stream>>>(part, x1, 4096, 256, 8, b_fpn1, nullptr, nullptr, nullptr, nullptr);
    gemm_v3<true><<<dim3(32, 4, 8), 128, 0, stream>>>(x1, w_fpn2, part, 4096, 256, 2304, 288);
    reduce_part<0><<<dim3(1024), 256, 0, stream>>>(part, x2, 4096, 256, 8, b_fpn2, nullptr, nullptr, nullptr, nullptr);
    gemm_v3<true><<<dim3(32, 8, 4), 128, 0, stream>>>(x2, w_rpn, part, 4096, 512, 2304, 576);
    reduce_part<1><<<dim3(2048), 256, 0, stream>>>(part, shr, 4096, 512, 4, b_rpn, nullptr, nullptr, nullptr, nullptr);
    // merged cls+dlt heads: [4096][512] @ [512][64]
    pack_heads<<<dim3(128), 256, 0, stream>>>(w_cls, w_dlt, b_cls, b_dlt, wCat, bCat);
    gemm_v3<false><<<dim3(32, 1, 8), 128, 0, stream>>>(shr, wCat, part, 4096, 64, 512, 64);
    reduce_part<0><<<dim3(256), 256, 0, stream>>>(part, hcat, 4096, 64, 8, bCat, nullptr, nullptr, nullptr, nullptr);
    rpn_probs_keys<<<dim3(144), 256, 0, stream>>>(hcat, out0, out1, keys);

    // ---- top-6000 (exact lax.top_k order) + NMS ----
    radix_select_compact<<<1, 1024, 0, stream>>>(keys, skeys);
    rank_decode<<<dim3(24), 256, 0, stream>>>(skeys, out1, image_h, image_w, props);
    nms_masks<<<dim3(24, 94), 256, 0, stream>>>(props, masksT, diag);
    // pipelined greedy NMS + writeout (block 0) + w_rc1 bf16-transpose (blocks 1..)
    nms_greedy_conv<<<dim3(1 + CONV_TILES), 1024, 0, stream>>>(masksT, diag, props, out2, w_rc1, wT);

    // ---- ROI head ----
    roi_align_k<<<dim3(1000), 256, 0, stream>>>(x2, out2, rois);
    h1_gemm<<<dim3(512), 256, 0, stream>>>(rois, wT, part);
    reduce_h1<<<dim3(4000), 256, 0, stream>>>(part, b_rc1, g1, be1, m1, v1, h1);
    gemm_v3<false><<<dim3(8, 16, 2), 128, 0, stream>>>(h1, w_rc2, part, 1000, 1024, 1024, 512);
    reduce_part<2><<<dim3(1000), 256, 0, stream>>>(part, h2, 1000, 1024, 2, b_rc2, g2, be2, m2, v2);
    // merged cls-logits + box heads: [1000][1024] @ [1024][512]
    pack_roi_heads<<<dim3(2048), 256, 0, stream>>>(w_log, w_bfc, b_log, b_bfc, wHead, bHead);
    gemm_v3<false><<<dim3(8, 8, 2), 128, 0, stream>>>(h2, wHead, part, 1000, 512, 1024, 512);
    reduce_part<0><<<dim3(500), 256, 0, stream>>>(part, hroi, 1000, 512, 2, bHead, nullptr, nullptr, nullptr, nullptr);
    split_roi<<<dim3(1266), 256, 0, stream>>>(hroi, out4);
    softmax_cls<<<dim3(1000), 128, 0, stream>>>(hroi, out3);
}